// Round 1
// baseline (5288.754 us; speedup 1.0000x reference)
//
#include <hip/hip_runtime.h>
#include <math.h>

#define BATCH 8
#define NPTS 2048
#define KNN 20
#define BN_TOTAL (BATCH * NPTS)
#define EPSV 1e-5f

// ---------------------------------------------------------------------------
// x2: per-row sum of squares
// ---------------------------------------------------------------------------
__global__ __launch_bounds__(256) void x2_kernel(const float* __restrict__ x, int C, int ldx,
                                                 float* __restrict__ x2) {
    int i = blockIdx.x * 256 + threadIdx.x;
    if (i >= BN_TOTAL) return;
    const float* xr = x + (size_t)i * ldx;
    float s = 0.f;
    for (int c = 0; c < C; ++c) s = fmaf(xr[c], xr[c], s);
    x2[i] = s;
}

// ---------------------------------------------------------------------------
// knn: one block per (b,n) row. Compute neg_dist to all 2048 points of the
// same batch into LDS, then 20 iterations of argmax (lowest-index tie-break).
// ---------------------------------------------------------------------------
__global__ __launch_bounds__(256) void knn_kernel(const float* __restrict__ x,
                                                  const float* __restrict__ x2,
                                                  int C, int ldx,
                                                  int* __restrict__ idx_out) {
    __shared__ float s_xi[128];
    __shared__ float s_d[NPTS];
    __shared__ float s_rv[256];
    __shared__ int   s_ri[256];
    __shared__ int   s_sel[KNN];

    int bn = blockIdx.x;
    int b = bn >> 11;
    int n = bn & 2047;
    const float* xb = x + (size_t)b * NPTS * ldx;
    const float* xr = xb + (size_t)n * ldx;
    for (int c = threadIdx.x; c < C; c += 256) s_xi[c] = xr[c];
    __syncthreads();

    float x2i = x2[bn];
    const float* x2b = x2 + (b << 11);

    if ((C & 3) == 0) {
        int C4 = C >> 2;
        for (int j = threadIdx.x; j < NPTS; j += 256) {
            const float4* xj = (const float4*)(xb + (size_t)j * ldx);
            float dot = 0.f;
            for (int c = 0; c < C4; ++c) {
                float4 a = ((const float4*)s_xi)[c];
                float4 v = xj[c];
                dot = fmaf(a.x, v.x, dot);
                dot = fmaf(a.y, v.y, dot);
                dot = fmaf(a.z, v.z, dot);
                dot = fmaf(a.w, v.w, dot);
            }
            s_d[j] = 2.f * dot - x2i - x2b[j];
        }
    } else {
        for (int j = threadIdx.x; j < NPTS; j += 256) {
            const float* xj = xb + (size_t)j * ldx;
            float dot = 0.f;
            for (int c = 0; c < C; ++c) dot = fmaf(s_xi[c], xj[c], dot);
            s_d[j] = 2.f * dot - x2i - x2b[j];
        }
    }
    __syncthreads();

    for (int it = 0; it < KNN; ++it) {
        float bv = -INFINITY;
        int   bi = 0x7fffffff;
        for (int j = threadIdx.x; j < NPTS; j += 256) {
            float v = s_d[j];
            if (v > bv) { bv = v; bi = j; }  // ascending j per thread -> lowest idx on tie
        }
        s_rv[threadIdx.x] = bv;
        s_ri[threadIdx.x] = bi;
        __syncthreads();
        for (int s = 128; s > 0; s >>= 1) {
            if (threadIdx.x < s) {
                float v2 = s_rv[threadIdx.x + s];
                int   i2 = s_ri[threadIdx.x + s];
                float v1 = s_rv[threadIdx.x];
                int   i1 = s_ri[threadIdx.x];
                if (v2 > v1 || (v2 == v1 && i2 < i1)) {
                    s_rv[threadIdx.x] = v2;
                    s_ri[threadIdx.x] = i2;
                }
            }
            __syncthreads();
        }
        if (threadIdx.x == 0) {
            int w = s_ri[0];
            s_sel[it] = w;
            s_d[w] = -INFINITY;
        }
        __syncthreads();
    }
    if (threadIdx.x < KNN) idx_out[bn * KNN + threadIdx.x] = s_sel[threadIdx.x];
}

// ---------------------------------------------------------------------------
// P/Q: P = x . W[:, 0:C]^T, Q = x . W[:, C:2C]^T   (one block per row)
// ---------------------------------------------------------------------------
__global__ __launch_bounds__(256) void pq_kernel(const float* __restrict__ x, int C, int ldx,
                                                 const float* __restrict__ W, int O,
                                                 float* __restrict__ P, float* __restrict__ Q) {
    __shared__ float s_xi[128];
    int bn = blockIdx.x;
    const float* xr = x + (size_t)bn * ldx;
    for (int c = threadIdx.x; c < C; c += 256) s_xi[c] = xr[c];
    __syncthreads();
    for (int o = threadIdx.x; o < O; o += 256) {
        const float* w = W + (size_t)o * 2 * C;
        float p = 0.f, q = 0.f;
        for (int c = 0; c < C; ++c) {
            p = fmaf(w[c], s_xi[c], p);
            q = fmaf(w[C + c], s_xi[c], q);
        }
        P[(size_t)bn * O + o] = p;
        Q[(size_t)bn * O + o] = q;
    }
}

// ---------------------------------------------------------------------------
// gather-max + BN + LeakyReLU epilogue (monotonicity: max/min on P per gamma sign)
// ---------------------------------------------------------------------------
__global__ __launch_bounds__(256) void gmax_kernel(const float* __restrict__ P,
                                                   const float* __restrict__ Q,
                                                   const int* __restrict__ idx, int O,
                                                   const float* __restrict__ gamma,
                                                   const float* __restrict__ beta,
                                                   float* __restrict__ out, int ldo) {
    __shared__ int s_idx[KNN];
    int bn = blockIdx.x;
    int b = bn >> 11;
    if (threadIdx.x < KNN) s_idx[threadIdx.x] = idx[bn * KNN + threadIdx.x];
    __syncthreads();
    const float inv = 1.0f / sqrtf(1.0f + EPSV);
    for (int o = threadIdx.x; o < O; o += 256) {
        float mx = -INFINITY, mn = INFINITY;
        for (int k = 0; k < KNN; ++k) {
            float v = P[((size_t)(b << 11) + s_idx[k]) * O + o];
            mx = fmaxf(mx, v);
            mn = fminf(mn, v);
        }
        float pn = P[(size_t)bn * O + o];
        float qn = Q[(size_t)bn * O + o];
        float sc = gamma[o] * inv;
        float m = (sc >= 0.f) ? mx : mn;
        float z = sc * (m - pn + qn) + beta[o];
        out[(size_t)bn * ldo + o] = (z >= 0.f) ? z : 0.2f * z;
    }
}

// ---------------------------------------------------------------------------
// final: feat = lrelu(bn(xcat @ W5^T)) then max & mean over N, per batch.
// One block handles 16 output channels of one batch.
// ---------------------------------------------------------------------------
#define OC 16
__global__ __launch_bounds__(256) void final_kernel(const float* __restrict__ xcat,
                                                    const float* __restrict__ W5,
                                                    const float* __restrict__ g5,
                                                    const float* __restrict__ b5,
                                                    float* __restrict__ out) {
    __shared__ float s_w[OC][512];
    __shared__ float s_red[256];
    int b = blockIdx.x >> 6;              // 64 o-chunks of 16
    int oc0 = (blockIdx.x & 63) * OC;

    for (int t = threadIdx.x; t < OC * 512; t += 256) {
        int oo = t >> 9, c = t & 511;
        s_w[oo][c] = W5[(size_t)(oc0 + oo) * 512 + c];
    }
    __syncthreads();

    float mx[OC], sm[OC];
    for (int o = 0; o < OC; ++o) { mx[o] = -INFINITY; sm[o] = 0.f; }
    const float inv = 1.0f / sqrtf(1.0f + EPSV);

    for (int n = threadIdx.x; n < NPTS; n += 256) {
        const float4* xr = (const float4*)(xcat + ((size_t)(b << 11) + n) * 512);
        float acc[OC];
        for (int o = 0; o < OC; ++o) acc[o] = 0.f;
        for (int c4 = 0; c4 < 128; ++c4) {
            float4 xv = xr[c4];
            for (int o = 0; o < OC; ++o) {
                float4 wv = ((const float4*)s_w[o])[c4];
                acc[o] = fmaf(xv.x, wv.x, acc[o]);
                acc[o] = fmaf(xv.y, wv.y, acc[o]);
                acc[o] = fmaf(xv.z, wv.z, acc[o]);
                acc[o] = fmaf(xv.w, wv.w, acc[o]);
            }
        }
        for (int o = 0; o < OC; ++o) {
            float sc = g5[oc0 + o] * inv;
            float z = sc * acc[o] + b5[oc0 + o];
            z = (z >= 0.f) ? z : 0.2f * z;
            mx[o] = fmaxf(mx[o], z);
            sm[o] += z;
        }
    }

    for (int o = 0; o < OC; ++o) {
        s_red[threadIdx.x] = mx[o];
        __syncthreads();
        for (int s = 128; s > 0; s >>= 1) {
            if (threadIdx.x < s) s_red[threadIdx.x] = fmaxf(s_red[threadIdx.x], s_red[threadIdx.x + s]);
            __syncthreads();
        }
        if (threadIdx.x == 0) out[(b << 11) + oc0 + o] = s_red[0];
        __syncthreads();
        s_red[threadIdx.x] = sm[o];
        __syncthreads();
        for (int s = 128; s > 0; s >>= 1) {
            if (threadIdx.x < s) s_red[threadIdx.x] += s_red[threadIdx.x + s];
            __syncthreads();
        }
        if (threadIdx.x == 0) out[(b << 11) + 1024 + oc0 + o] = s_red[0] * (1.0f / 2048.0f);
        __syncthreads();
    }
}

// ---------------------------------------------------------------------------
extern "C" void kernel_launch(void* const* d_in, const int* in_sizes, int n_in,
                              void* d_out, int out_size, void* d_ws, size_t ws_size,
                              hipStream_t stream) {
    const float* points = (const float*)d_in[0];
    const float* W1 = (const float*)d_in[1];
    const float* W2 = (const float*)d_in[2];
    const float* W3 = (const float*)d_in[3];
    const float* W4 = (const float*)d_in[4];
    const float* W5 = (const float*)d_in[5];
    const float* g1 = (const float*)d_in[6];
    const float* b1 = (const float*)d_in[7];
    const float* g2 = (const float*)d_in[8];
    const float* b2 = (const float*)d_in[9];
    const float* g3 = (const float*)d_in[10];
    const float* b3 = (const float*)d_in[11];
    const float* g4 = (const float*)d_in[12];
    const float* b4 = (const float*)d_in[13];
    const float* g5 = (const float*)d_in[14];
    const float* b5 = (const float*)d_in[15];
    float* out = (float*)d_out;

    // workspace layout (floats)
    float* xcat = (float*)d_ws;                       // BN_TOTAL * 512
    float* P    = xcat + (size_t)BN_TOTAL * 512;      // BN_TOTAL * 256
    float* Q    = P + (size_t)BN_TOTAL * 256;         // BN_TOTAL * 256
    float* x2   = Q + (size_t)BN_TOTAL * 256;         // BN_TOTAL
    int*   idx  = (int*)(x2 + BN_TOTAL);              // BN_TOTAL * KNN

    auto layer = [&](const float* xin, int C, int ldx, const float* W, int O,
                     const float* ga, const float* be, float* xout, int ldo) {
        x2_kernel<<<(BN_TOTAL + 255) / 256, 256, 0, stream>>>(xin, C, ldx, x2);
        knn_kernel<<<BN_TOTAL, 256, 0, stream>>>(xin, x2, C, ldx, idx);
        pq_kernel<<<BN_TOTAL, 256, 0, stream>>>(xin, C, ldx, W, O, P, Q);
        gmax_kernel<<<BN_TOTAL, 256, 0, stream>>>(P, Q, idx, O, ga, be, xout, ldo);
    };

    layer(points,     3,   3,   W1, 64,  g1, b1, xcat + 0,   512);
    layer(xcat + 0,   64,  512, W2, 64,  g2, b2, xcat + 64,  512);
    layer(xcat + 64,  64,  512, W3, 128, g3, b3, xcat + 128, 512);
    layer(xcat + 128, 128, 512, W4, 256, g4, b4, xcat + 256, 512);

    final_kernel<<<BATCH * 64, 256, 0, stream>>>(xcat, W5, g5, b5, out);
}

// Round 2
// 1373.322 us; speedup vs baseline: 3.8511x; 3.8511x over previous
//
#include <hip/hip_runtime.h>
#include <math.h>

#define BATCH 8
#define NPTS 2048
#define KNN 20
#define BN_TOTAL (BATCH * NPTS)
#define EPSV 1e-5f

// ---------------------------------------------------------------------------
// x2: per-row sum of squares
// ---------------------------------------------------------------------------
__global__ __launch_bounds__(256) void x2_kernel(const float* __restrict__ x, int C, int ldx,
                                                 float* __restrict__ x2) {
    int i = blockIdx.x * 256 + threadIdx.x;
    if (i >= BN_TOTAL) return;
    const float* xr = x + (size_t)i * ldx;
    float s = 0.f;
    for (int c = 0; c < C; ++c) s = fmaf(xr[c], xr[c], s);
    x2[i] = s;
}

// ---------------------------------------------------------------------------
// dist: tiled GEMM computing neg_dist S[z*2048+i][j] = 2*dot(xi,xj) - x2i - x2j
// for batches b0..b0+gridDim.z-1. BM=BN=64, BK=32, 256 thr, 4x4 micro-tile.
// ---------------------------------------------------------------------------
__global__ __launch_bounds__(256) void dist_kernel(const float* __restrict__ x,
                                                   const float* __restrict__ x2,
                                                   int C, int ldx, int b0,
                                                   float* __restrict__ S) {
    __shared__ float As[32][68];
    __shared__ float Bs[32][68];
    int z = blockIdx.z;
    int b = b0 + z;
    int i0 = blockIdx.x * 64, j0 = blockIdx.y * 64;
    const float* xb = x + (size_t)b * NPTS * ldx;
    int tid = threadIdx.x;
    int tm = tid >> 4, tn = tid & 15;

    float acc[4][4] = {};
    int KT = (C + 31) >> 5;
    for (int kt = 0; kt < KT; ++kt) {
        int k0 = kt << 5;
        for (int e = tid; e < 2048; e += 256) {
            int m = e >> 5, k = e & 31;
            int kk = k0 + k;
            As[k][m] = (kk < C) ? xb[(size_t)(i0 + m) * ldx + kk] : 0.f;
            Bs[k][m] = (kk < C) ? xb[(size_t)(j0 + m) * ldx + kk] : 0.f;
        }
        __syncthreads();
#pragma unroll
        for (int k = 0; k < 32; ++k) {
            float4 a = *(const float4*)&As[k][tm * 4];
            float4 bb = *(const float4*)&Bs[k][tn * 4];
            acc[0][0] = fmaf(a.x, bb.x, acc[0][0]); acc[0][1] = fmaf(a.x, bb.y, acc[0][1]);
            acc[0][2] = fmaf(a.x, bb.z, acc[0][2]); acc[0][3] = fmaf(a.x, bb.w, acc[0][3]);
            acc[1][0] = fmaf(a.y, bb.x, acc[1][0]); acc[1][1] = fmaf(a.y, bb.y, acc[1][1]);
            acc[1][2] = fmaf(a.y, bb.z, acc[1][2]); acc[1][3] = fmaf(a.y, bb.w, acc[1][3]);
            acc[2][0] = fmaf(a.z, bb.x, acc[2][0]); acc[2][1] = fmaf(a.z, bb.y, acc[2][1]);
            acc[2][2] = fmaf(a.z, bb.z, acc[2][2]); acc[2][3] = fmaf(a.z, bb.w, acc[2][3]);
            acc[3][0] = fmaf(a.w, bb.x, acc[3][0]); acc[3][1] = fmaf(a.w, bb.y, acc[3][1]);
            acc[3][2] = fmaf(a.w, bb.z, acc[3][2]); acc[3][3] = fmaf(a.w, bb.w, acc[3][3]);
        }
        __syncthreads();
    }

    const float* x2b = x2 + (size_t)b * NPTS;
    float xj0 = x2b[j0 + tn * 4 + 0], xj1 = x2b[j0 + tn * 4 + 1];
    float xj2 = x2b[j0 + tn * 4 + 2], xj3 = x2b[j0 + tn * 4 + 3];
#pragma unroll
    for (int mi = 0; mi < 4; ++mi) {
        float xi = x2b[i0 + tm * 4 + mi];
        float4 o;
        o.x = 2.f * acc[mi][0] - xi - xj0;
        o.y = 2.f * acc[mi][1] - xi - xj1;
        o.z = 2.f * acc[mi][2] - xi - xj2;
        o.w = 2.f * acc[mi][3] - xi - xj3;
        *(float4*)&S[((size_t)z * NPTS + i0 + tm * 4 + mi) * NPTS + j0 + tn * 4] = o;
    }
}

// ---------------------------------------------------------------------------
// topk: one wave per row; 32 values/lane in registers; 20 shfl-argmax iters.
// ---------------------------------------------------------------------------
__global__ __launch_bounds__(256) void topk_kernel(const float* __restrict__ S, int b0,
                                                   int* __restrict__ idx_out) {
    int lane = threadIdx.x & 63, w = threadIdx.x >> 6;
    int row = blockIdx.x * 4 + w;
    const float4* S4 = (const float4*)(S + (size_t)row * NPTS);

    float v[32];
    float lm = -INFINITY; int li = 0;
#pragma unroll
    for (int r4 = 0; r4 < 8; ++r4) {
        float4 f = S4[lane * 8 + r4];
        v[r4 * 4 + 0] = f.x; v[r4 * 4 + 1] = f.y;
        v[r4 * 4 + 2] = f.z; v[r4 * 4 + 3] = f.w;
    }
#pragma unroll
    for (int q = 0; q < 32; ++q)
        if (v[q] > lm) { lm = v[q]; li = q; }

    int sel = 0;
    for (int it = 0; it < KNN; ++it) {
        float bv = lm;
        int bi = (lane << 5) | li;
#pragma unroll
        for (int d = 1; d < 64; d <<= 1) {
            float ov = __shfl_xor(bv, d);
            int oi = __shfl_xor(bi, d);
            if (ov > bv || (ov == bv && oi < bi)) { bv = ov; bi = oi; }
        }
        if (lane == it) sel = bi;
        if ((bi >> 5) == lane) {
            int r = bi & 31;
#pragma unroll
            for (int q = 0; q < 32; ++q)
                if (q == r) v[q] = -INFINITY;
            lm = -INFINITY; li = 0;
#pragma unroll
            for (int q = 0; q < 32; ++q)
                if (v[q] > lm) { lm = v[q]; li = q; }
        }
    }
    int z = row >> 11, i = row & 2047;
    int bn = (b0 + z) * NPTS + i;
    if (lane < KNN) idx_out[bn * KNN + lane] = sel;
}

// ---------------------------------------------------------------------------
// pq_gemm: PQ[bn][0..O)=x.Wp^T, PQ[bn][O..2O)=x.Wq^T as one GEMM (N=2O).
// ---------------------------------------------------------------------------
__global__ __launch_bounds__(256) void pq_gemm(const float* __restrict__ X, int C, int ldx,
                                               const float* __restrict__ W, int O,
                                               float* __restrict__ PQ) {
    __shared__ float As[32][68];
    __shared__ float Bs[32][68];
    int i0 = blockIdx.x * 64, j0 = blockIdx.y * 64;
    int tid = threadIdx.x;
    int tm = tid >> 4, tn = tid & 15;
    int N2 = 2 * O;

    float acc[4][4] = {};
    int KT = (C + 31) >> 5;
    for (int kt = 0; kt < KT; ++kt) {
        int k0 = kt << 5;
        for (int e = tid; e < 2048; e += 256) {
            int m = e >> 5, k = e & 31;
            int kk = k0 + k;
            As[k][m] = (kk < C) ? X[(size_t)(i0 + m) * ldx + kk] : 0.f;
            int o = j0 + m;
            float wv = 0.f;
            if (kk < C)
                wv = (o < O) ? W[(size_t)o * 2 * C + kk] : W[(size_t)(o - O) * 2 * C + C + kk];
            Bs[k][m] = wv;
        }
        __syncthreads();
#pragma unroll
        for (int k = 0; k < 32; ++k) {
            float4 a = *(const float4*)&As[k][tm * 4];
            float4 bb = *(const float4*)&Bs[k][tn * 4];
            acc[0][0] = fmaf(a.x, bb.x, acc[0][0]); acc[0][1] = fmaf(a.x, bb.y, acc[0][1]);
            acc[0][2] = fmaf(a.x, bb.z, acc[0][2]); acc[0][3] = fmaf(a.x, bb.w, acc[0][3]);
            acc[1][0] = fmaf(a.y, bb.x, acc[1][0]); acc[1][1] = fmaf(a.y, bb.y, acc[1][1]);
            acc[1][2] = fmaf(a.y, bb.z, acc[1][2]); acc[1][3] = fmaf(a.y, bb.w, acc[1][3]);
            acc[2][0] = fmaf(a.z, bb.x, acc[2][0]); acc[2][1] = fmaf(a.z, bb.y, acc[2][1]);
            acc[2][2] = fmaf(a.z, bb.z, acc[2][2]); acc[2][3] = fmaf(a.z, bb.w, acc[2][3]);
            acc[3][0] = fmaf(a.w, bb.x, acc[3][0]); acc[3][1] = fmaf(a.w, bb.y, acc[3][1]);
            acc[3][2] = fmaf(a.w, bb.z, acc[3][2]); acc[3][3] = fmaf(a.w, bb.w, acc[3][3]);
        }
        __syncthreads();
    }
#pragma unroll
    for (int mi = 0; mi < 4; ++mi) {
        float4 o;
        o.x = acc[mi][0]; o.y = acc[mi][1]; o.z = acc[mi][2]; o.w = acc[mi][3];
        *(float4*)&PQ[(size_t)(i0 + tm * 4 + mi) * N2 + j0 + tn * 4] = o;
    }
}

// ---------------------------------------------------------------------------
// gather-max + BN + LeakyReLU epilogue
// ---------------------------------------------------------------------------
__global__ __launch_bounds__(256) void gmax_kernel(const float* __restrict__ PQ,
                                                   const int* __restrict__ idx, int O,
                                                   const float* __restrict__ gamma,
                                                   const float* __restrict__ beta,
                                                   float* __restrict__ out, int ldo) {
    __shared__ int s_idx[KNN];
    int bn = blockIdx.x;
    int b = bn >> 11;
    if (threadIdx.x < KNN) s_idx[threadIdx.x] = idx[bn * KNN + threadIdx.x];
    __syncthreads();
    const float inv = 1.0f / sqrtf(1.0f + EPSV);
    int N2 = 2 * O;
    size_t brow = (size_t)(b << 11);
    for (int o = threadIdx.x; o < O; o += 256) {
        float mx = -INFINITY, mn = INFINITY;
        for (int k = 0; k < KNN; ++k) {
            float v = PQ[(brow + s_idx[k]) * N2 + o];
            mx = fmaxf(mx, v);
            mn = fminf(mn, v);
        }
        float pn = PQ[(size_t)bn * N2 + o];
        float qn = PQ[(size_t)bn * N2 + O + o];
        float sc = gamma[o] * inv;
        float m = (sc >= 0.f) ? mx : mn;
        float z = sc * (m - pn + qn) + beta[o];
        out[(size_t)bn * ldo + o] = (z >= 0.f) ? z : 0.2f * z;
    }
}

// ---------------------------------------------------------------------------
// final: partial (max,sum) per (b, ochunk, nchunk); then reduce.
// ---------------------------------------------------------------------------
#define OC 16
#define NCH 4
__global__ __launch_bounds__(256) void final_kernel(const float* __restrict__ xcat,
                                                    const float* __restrict__ W5,
                                                    const float* __restrict__ g5,
                                                    const float* __restrict__ b5,
                                                    float* __restrict__ part) {
    __shared__ float s_w[OC][512];
    __shared__ float s_red[2][4][OC];
    int nc = blockIdx.x & 3;
    int oc = (blockIdx.x >> 2) & 63;
    int b = blockIdx.x >> 8;
    int oc0 = oc * OC;

    for (int t = threadIdx.x; t < OC * 512; t += 256) {
        int oo = t >> 9, c = t & 511;
        s_w[oo][c] = W5[(size_t)(oc0 + oo) * 512 + c];
    }
    __syncthreads();

    const float inv = 1.0f / sqrtf(1.0f + EPSV);
    float sc[OC], bi[OC];
#pragma unroll
    for (int o = 0; o < OC; ++o) { sc[o] = g5[oc0 + o] * inv; bi[o] = b5[oc0 + o]; }

    float mx[OC], sm[OC];
#pragma unroll
    for (int o = 0; o < OC; ++o) { mx[o] = -INFINITY; sm[o] = 0.f; }

    for (int n = nc * 512 + threadIdx.x; n < (nc + 1) * 512; n += 256) {
        const float4* xr = (const float4*)(xcat + ((size_t)(b << 11) + n) * 512);
        float acc[OC];
#pragma unroll
        for (int o = 0; o < OC; ++o) acc[o] = 0.f;
        for (int c4 = 0; c4 < 128; ++c4) {
            float4 xv = xr[c4];
#pragma unroll
            for (int o = 0; o < OC; ++o) {
                float4 wv = ((const float4*)s_w[o])[c4];
                acc[o] = fmaf(xv.x, wv.x, acc[o]);
                acc[o] = fmaf(xv.y, wv.y, acc[o]);
                acc[o] = fmaf(xv.z, wv.z, acc[o]);
                acc[o] = fmaf(xv.w, wv.w, acc[o]);
            }
        }
#pragma unroll
        for (int o = 0; o < OC; ++o) {
            float z = fmaf(sc[o], acc[o], bi[o]);
            z = (z >= 0.f) ? z : 0.2f * z;
            mx[o] = fmaxf(mx[o], z);
            sm[o] += z;
        }
    }

    int lane = threadIdx.x & 63, w = threadIdx.x >> 6;
#pragma unroll
    for (int o = 0; o < OC; ++o) {
        float m = mx[o], s = sm[o];
#pragma unroll
        for (int d = 1; d < 64; d <<= 1) {
            m = fmaxf(m, __shfl_xor(m, d));
            s += __shfl_xor(s, d);
        }
        if (lane == 0) { s_red[0][w][o] = m; s_red[1][w][o] = s; }
    }
    __syncthreads();
    if (threadIdx.x < OC) {
        int o = threadIdx.x;
        float m = fmaxf(fmaxf(s_red[0][0][o], s_red[0][1][o]),
                        fmaxf(s_red[0][2][o], s_red[0][3][o]));
        float s = s_red[1][0][o] + s_red[1][1][o] + s_red[1][2][o] + s_red[1][3][o];
        size_t base = (((size_t)b * 64 + oc) * NCH + nc) * 32;
        part[base + o] = m;
        part[base + 16 + o] = s;
    }
}

__global__ __launch_bounds__(256) void freduce_kernel(const float* __restrict__ part,
                                                      float* __restrict__ out) {
    int t = blockIdx.x * 256 + threadIdx.x;
    if (t >= 8 * 1024) return;
    int b = t >> 10, o = t & 1023;
    int oc = o >> 4, oo = o & 15;
    size_t base = (((size_t)b * 64 + oc) * NCH) * 32 + oo;
    float m = -INFINITY, s = 0.f;
#pragma unroll
    for (int nc = 0; nc < NCH; ++nc) {
        m = fmaxf(m, part[base + nc * 32]);
        s += part[base + nc * 32 + 16];
    }
    out[b * 2048 + o] = m;
    out[b * 2048 + 1024 + o] = s * (1.0f / 2048.0f);
}

// ---------------------------------------------------------------------------
extern "C" void kernel_launch(void* const* d_in, const int* in_sizes, int n_in,
                              void* d_out, int out_size, void* d_ws, size_t ws_size,
                              hipStream_t stream) {
    const float* points = (const float*)d_in[0];
    const float* W1 = (const float*)d_in[1];
    const float* W2 = (const float*)d_in[2];
    const float* W3 = (const float*)d_in[3];
    const float* W4 = (const float*)d_in[4];
    const float* W5 = (const float*)d_in[5];
    const float* g1 = (const float*)d_in[6];
    const float* b1 = (const float*)d_in[7];
    const float* g2 = (const float*)d_in[8];
    const float* b2 = (const float*)d_in[9];
    const float* g3 = (const float*)d_in[10];
    const float* b3 = (const float*)d_in[11];
    const float* g4 = (const float*)d_in[12];
    const float* b4 = (const float*)d_in[13];
    const float* g5 = (const float*)d_in[14];
    const float* b5 = (const float*)d_in[15];
    float* out = (float*)d_out;

    // chunk size (batches per dist/topk pass) chosen by workspace capacity
    const size_t f_xcat = (size_t)BN_TOTAL * 512;     // 8,388,608
    const size_t f_x2 = BN_TOTAL;
    const size_t f_idx = (size_t)BN_TOTAL * KNN;      // ints
    const size_t f_part = (size_t)8 * 64 * NCH * 32;
    const size_t fixedf = f_xcat + f_x2 + f_idx + f_part;
    auto needB = [&](int c) {
        size_t spq = (size_t)c * NPTS * NPTS;
        if (spq < f_xcat) spq = f_xcat;                // PQ needs 16384*512
        return 4ull * (fixedf + spq);
    };
    int cB = 2;
    if (ws_size >= needB(8)) cB = 8;
    else if (ws_size >= needB(4)) cB = 4;
    size_t spq_f = (size_t)cB * NPTS * NPTS;
    if (spq_f < f_xcat) spq_f = f_xcat;

    float* xcat = (float*)d_ws;                        // BN_TOTAL * 512
    float* SPQ = xcat + f_xcat;                        // S chunk / PQ (union)
    float* x2 = SPQ + spq_f;
    int* idx = (int*)(x2 + f_x2);
    float* part = (float*)(idx + f_idx);

    auto layer = [&](const float* xin, int C, int ldx, const float* W, int O,
                     const float* ga, const float* be, float* xout) {
        x2_kernel<<<(BN_TOTAL + 255) / 256, 256, 0, stream>>>(xin, C, ldx, x2);
        for (int b0 = 0; b0 < BATCH; b0 += cB) {
            dist_kernel<<<dim3(32, 32, cB), 256, 0, stream>>>(xin, x2, C, ldx, b0, SPQ);
            topk_kernel<<<cB * 512, 256, 0, stream>>>(SPQ, b0, idx);
        }
        pq_gemm<<<dim3(BN_TOTAL / 64, (2 * O) / 64), 256, 0, stream>>>(xin, C, ldx, W, O, SPQ);
        gmax_kernel<<<BN_TOTAL, 256, 0, stream>>>(SPQ, idx, O, ga, be, xout, 512);
    };

    layer(points,     3,   3,   W1, 64,  g1, b1, xcat + 0);
    layer(xcat + 0,   64,  512, W2, 64,  g2, b2, xcat + 64);
    layer(xcat + 64,  64,  512, W3, 128, g3, b3, xcat + 128);
    layer(xcat + 128, 128, 512, W4, 256, g4, b4, xcat + 256);

    final_kernel<<<8 * 64 * NCH, 256, 0, stream>>>(xcat, W5, g5, b5, part);
    freduce_kernel<<<(8 * 1024 + 255) / 256, 256, 0, stream>>>(part, out);
}

// Round 3
// 1108.580 us; speedup vs baseline: 4.7707x; 1.2388x over previous
//
#include <hip/hip_runtime.h>
#include <math.h>

#define BATCH 8
#define NPTS 2048
#define KNN 20
#define BN_TOTAL (BATCH * NPTS)
#define EPSV 1e-5f

// ---------------------------------------------------------------------------
// x2: per-row sum of squares
// ---------------------------------------------------------------------------
__global__ __launch_bounds__(256) void x2_kernel(const float* __restrict__ x, int C, int ldx,
                                                 float* __restrict__ x2) {
    int i = blockIdx.x * 256 + threadIdx.x;
    if (i >= BN_TOTAL) return;
    const float* xr = x + (size_t)i * ldx;
    float s = 0.f;
    if ((ldx & 3) == 0 && (C & 3) == 0) {
        const float4* xr4 = (const float4*)xr;
        for (int c = 0; c < (C >> 2); ++c) {
            float4 v = xr4[c];
            s = fmaf(v.x, v.x, s); s = fmaf(v.y, v.y, s);
            s = fmaf(v.z, v.z, s); s = fmaf(v.w, v.w, s);
        }
    } else {
        for (int c = 0; c < C; ++c) s = fmaf(xr[c], xr[c], s);
    }
    x2[i] = s;
}

// ---------------------------------------------------------------------------
// dist: tiled GEMM, neg_dist S[z*2048+i][j] = 2*dot(xi,xj) - x2i - x2j.
// 128x128 tile, BK=16, 256 thr, 8x8 micro-tile.
// ---------------------------------------------------------------------------
__global__ __launch_bounds__(256) void dist_kernel(const float* __restrict__ x,
                                                   const float* __restrict__ x2,
                                                   int C, int ldx, int b0,
                                                   float* __restrict__ S) {
    __shared__ float As[16][136];
    __shared__ float Bs[16][136];
    int z = blockIdx.z;
    int b = b0 + z;
    int i0 = blockIdx.x * 128, j0 = blockIdx.y * 128;
    const float* xb = x + (size_t)b * NPTS * ldx;
    int tid = threadIdx.x;
    int tm = tid >> 4, tn = tid & 15;

    float acc[8][8] = {};
    int KT = (C + 15) >> 4;
    for (int kt = 0; kt < KT; ++kt) {
        int k0 = kt << 4;
#pragma unroll
        for (int s = tid; s < 512; s += 256) {
            int r = s >> 2, c4 = s & 3;
            int kk = k0 + c4 * 4;
            float va[4], vb[4];
            if (kk + 3 < C && (ldx & 3) == 0) {
                float4 a = *(const float4*)&xb[(size_t)(i0 + r) * ldx + kk];
                float4 bv = *(const float4*)&xb[(size_t)(j0 + r) * ldx + kk];
                va[0] = a.x; va[1] = a.y; va[2] = a.z; va[3] = a.w;
                vb[0] = bv.x; vb[1] = bv.y; vb[2] = bv.z; vb[3] = bv.w;
            } else {
#pragma unroll
                for (int u = 0; u < 4; ++u) {
                    int k = kk + u;
                    va[u] = (k < C) ? xb[(size_t)(i0 + r) * ldx + k] : 0.f;
                    vb[u] = (k < C) ? xb[(size_t)(j0 + r) * ldx + k] : 0.f;
                }
            }
#pragma unroll
            for (int u = 0; u < 4; ++u) {
                As[c4 * 4 + u][r] = va[u];
                Bs[c4 * 4 + u][r] = vb[u];
            }
        }
        __syncthreads();
#pragma unroll
        for (int k = 0; k < 16; ++k) {
            float4 a0 = *(const float4*)&As[k][tm * 8];
            float4 a1 = *(const float4*)&As[k][tm * 8 + 4];
            float4 c0 = *(const float4*)&Bs[k][tn * 8];
            float4 c1 = *(const float4*)&Bs[k][tn * 8 + 4];
            float av[8] = {a0.x, a0.y, a0.z, a0.w, a1.x, a1.y, a1.z, a1.w};
            float bv[8] = {c0.x, c0.y, c0.z, c0.w, c1.x, c1.y, c1.z, c1.w};
#pragma unroll
            for (int mi = 0; mi < 8; ++mi)
#pragma unroll
                for (int ni = 0; ni < 8; ++ni)
                    acc[mi][ni] = fmaf(av[mi], bv[ni], acc[mi][ni]);
        }
        __syncthreads();
    }

    const float* x2b = x2 + (size_t)b * NPTS;
    float xj[8];
#pragma unroll
    for (int u = 0; u < 8; ++u) xj[u] = x2b[j0 + tn * 8 + u];
#pragma unroll
    for (int mi = 0; mi < 8; ++mi) {
        float xi = x2b[i0 + tm * 8 + mi];
        float4 o0, o1;
        o0.x = 2.f * acc[mi][0] - xi - xj[0];
        o0.y = 2.f * acc[mi][1] - xi - xj[1];
        o0.z = 2.f * acc[mi][2] - xi - xj[2];
        o0.w = 2.f * acc[mi][3] - xi - xj[3];
        o1.x = 2.f * acc[mi][4] - xi - xj[4];
        o1.y = 2.f * acc[mi][5] - xi - xj[5];
        o1.z = 2.f * acc[mi][6] - xi - xj[6];
        o1.w = 2.f * acc[mi][7] - xi - xj[7];
        size_t rowp = ((size_t)z * NPTS + i0 + tm * 8 + mi) * NPTS + j0 + tn * 8;
        *(float4*)&S[rowp] = o0;
        *(float4*)&S[rowp + 4] = o1;
    }
}

// ---------------------------------------------------------------------------
// topk: one wave per row; 32 values/lane in registers; 20 shfl-argmax iters.
// ---------------------------------------------------------------------------
__global__ __launch_bounds__(256) void topk_kernel(const float* __restrict__ S, int b0,
                                                   int* __restrict__ idx_out) {
    int lane = threadIdx.x & 63, w = threadIdx.x >> 6;
    int row = blockIdx.x * 4 + w;
    const float4* S4 = (const float4*)(S + (size_t)row * NPTS);

    float v[32];
    float lm = -INFINITY; int li = 0;
#pragma unroll
    for (int r4 = 0; r4 < 8; ++r4) {
        float4 f = S4[lane * 8 + r4];
        v[r4 * 4 + 0] = f.x; v[r4 * 4 + 1] = f.y;
        v[r4 * 4 + 2] = f.z; v[r4 * 4 + 3] = f.w;
    }
#pragma unroll
    for (int q = 0; q < 32; ++q)
        if (v[q] > lm) { lm = v[q]; li = q; }

    int sel = 0;
    for (int it = 0; it < KNN; ++it) {
        float bv = lm;
        int bi = (lane << 5) | li;
#pragma unroll
        for (int d = 1; d < 64; d <<= 1) {
            float ov = __shfl_xor(bv, d);
            int oi = __shfl_xor(bi, d);
            if (ov > bv || (ov == bv && oi < bi)) { bv = ov; bi = oi; }
        }
        if (lane == it) sel = bi;
        if ((bi >> 5) == lane) {
            int r = bi & 31;
#pragma unroll
            for (int q = 0; q < 32; ++q)
                if (q == r) v[q] = -INFINITY;
            lm = -INFINITY; li = 0;
#pragma unroll
            for (int q = 0; q < 32; ++q)
                if (v[q] > lm) { lm = v[q]; li = q; }
        }
    }
    int z = row >> 11, i = row & 2047;
    int bn = (b0 + z) * NPTS + i;
    if (lane < KNN) idx_out[bn * KNN + lane] = sel;
}

// ---------------------------------------------------------------------------
// pq_gemm: PQ[bn][0..O)=x.Wp^T, PQ[bn][O..2O)=x.Wq^T as one GEMM (N=2O).
// ---------------------------------------------------------------------------
__global__ __launch_bounds__(256) void pq_gemm(const float* __restrict__ X, int C, int ldx,
                                               const float* __restrict__ W, int O,
                                               float* __restrict__ PQ) {
    __shared__ float As[32][68];
    __shared__ float Bs[32][68];
    int i0 = blockIdx.x * 64, j0 = blockIdx.y * 64;
    int tid = threadIdx.x;
    int tm = tid >> 4, tn = tid & 15;
    int N2 = 2 * O;

    float acc[4][4] = {};
    int KT = (C + 31) >> 5;
    for (int kt = 0; kt < KT; ++kt) {
        int k0 = kt << 5;
        for (int e = tid; e < 2048; e += 256) {
            int m = e >> 5, k = e & 31;
            int kk = k0 + k;
            As[k][m] = (kk < C) ? X[(size_t)(i0 + m) * ldx + kk] : 0.f;
            int o = j0 + m;
            float wv = 0.f;
            if (kk < C)
                wv = (o < O) ? W[(size_t)o * 2 * C + kk] : W[(size_t)(o - O) * 2 * C + C + kk];
            Bs[k][m] = wv;
        }
        __syncthreads();
#pragma unroll
        for (int k = 0; k < 32; ++k) {
            float4 a = *(const float4*)&As[k][tm * 4];
            float4 bb = *(const float4*)&Bs[k][tn * 4];
            float av[4] = {a.x, a.y, a.z, a.w};
            float bv[4] = {bb.x, bb.y, bb.z, bb.w};
#pragma unroll
            for (int mi = 0; mi < 4; ++mi)
#pragma unroll
                for (int ni = 0; ni < 4; ++ni)
                    acc[mi][ni] = fmaf(av[mi], bv[ni], acc[mi][ni]);
        }
        __syncthreads();
    }
#pragma unroll
    for (int mi = 0; mi < 4; ++mi) {
        float4 o;
        o.x = acc[mi][0]; o.y = acc[mi][1]; o.z = acc[mi][2]; o.w = acc[mi][3];
        *(float4*)&PQ[(size_t)(i0 + tm * 4 + mi) * N2 + j0 + tn * 4] = o;
    }
}

// ---------------------------------------------------------------------------
// gather-max + BN + LeakyReLU epilogue. 256/O rows per block, all lanes busy.
// ---------------------------------------------------------------------------
__global__ __launch_bounds__(256) void gmax_kernel(const float* __restrict__ PQ,
                                                   const int* __restrict__ idx, int O, int oshift,
                                                   const float* __restrict__ gamma,
                                                   const float* __restrict__ beta,
                                                   float* __restrict__ out, int ldo) {
    __shared__ int s_idx[4][KNN];
    int rpb = 256 >> oshift;                 // O in {64,128,256}
    int lr = threadIdx.x >> oshift;
    int o = threadIdx.x & (O - 1);
    int bn = blockIdx.x * rpb + lr;
    int b = bn >> 11;
    if (o < KNN) s_idx[lr][o] = idx[bn * KNN + o];
    __syncthreads();
    const float inv = 1.0f / sqrtf(1.0f + EPSV);
    int N2 = 2 * O;
    size_t brow = (size_t)(b << 11);
    float mx = -INFINITY, mn = INFINITY;
#pragma unroll
    for (int k = 0; k < KNN; ++k) {
        float v = PQ[(brow + s_idx[lr][k]) * N2 + o];
        mx = fmaxf(mx, v);
        mn = fminf(mn, v);
    }
    float pn = PQ[(size_t)bn * N2 + o];
    float qn = PQ[(size_t)bn * N2 + O + o];
    float sc = gamma[o] * inv;
    float m = (sc >= 0.f) ? mx : mn;
    float z = sc * (m - pn + qn) + beta[o];
    out[(size_t)bn * ldo + o] = (z >= 0.f) ? z : 0.2f * z;
}

// ---------------------------------------------------------------------------
// final GEMM: feat = lrelu(bn(xcat @ W5^T)); fused partial max/sum over the
// block's 128 n-rows. 128x128 tile, BK=16, 8x8 micro-tile.
// part layout: [(b*16+nt)*2 + {0:max,1:sum}][1024]
// ---------------------------------------------------------------------------
__global__ __launch_bounds__(256) void final_gemm(const float* __restrict__ xcat,
                                                  const float* __restrict__ W5,
                                                  const float* __restrict__ g5,
                                                  const float* __restrict__ b5,
                                                  float* __restrict__ part) {
    __shared__ float As[16][136];
    __shared__ float Bs[16][136];
    __shared__ float s_red[2][16][132];
    int i0 = blockIdx.x * 128;               // n-row
    int j0 = blockIdx.y * 128;               // o
    int tid = threadIdx.x;
    int tm = tid >> 4, tn = tid & 15;

    float acc[8][8] = {};
    for (int kt = 0; kt < 32; ++kt) {
        int k0 = kt << 4;
#pragma unroll
        for (int s = tid; s < 512; s += 256) {
            int r = s >> 2, c4 = s & 3;
            int kk = k0 + c4 * 4;
            float4 va = *(const float4*)&xcat[(size_t)(i0 + r) * 512 + kk];
            float4 vb = *(const float4*)&W5[(size_t)(j0 + r) * 512 + kk];
            As[c4 * 4 + 0][r] = va.x; As[c4 * 4 + 1][r] = va.y;
            As[c4 * 4 + 2][r] = va.z; As[c4 * 4 + 3][r] = va.w;
            Bs[c4 * 4 + 0][r] = vb.x; Bs[c4 * 4 + 1][r] = vb.y;
            Bs[c4 * 4 + 2][r] = vb.z; Bs[c4 * 4 + 3][r] = vb.w;
        }
        __syncthreads();
#pragma unroll
        for (int k = 0; k < 16; ++k) {
            float4 a0 = *(const float4*)&As[k][tm * 8];
            float4 a1 = *(const float4*)&As[k][tm * 8 + 4];
            float4 c0 = *(const float4*)&Bs[k][tn * 8];
            float4 c1 = *(const float4*)&Bs[k][tn * 8 + 4];
            float av[8] = {a0.x, a0.y, a0.z, a0.w, a1.x, a1.y, a1.z, a1.w};
            float bv[8] = {c0.x, c0.y, c0.z, c0.w, c1.x, c1.y, c1.z, c1.w};
#pragma unroll
            for (int mi = 0; mi < 8; ++mi)
#pragma unroll
                for (int ni = 0; ni < 8; ++ni)
                    acc[mi][ni] = fmaf(av[mi], bv[ni], acc[mi][ni]);
        }
        __syncthreads();
    }

    const float inv = 1.0f / sqrtf(1.0f + EPSV);
#pragma unroll
    for (int u = 0; u < 8; ++u) {
        int o = j0 + tn * 8 + u;
        float sc = g5[o] * inv;
        float bi = b5[o];
        float mx = -INFINITY, sm = 0.f;
#pragma unroll
        for (int mi = 0; mi < 8; ++mi) {
            float z = fmaf(sc, acc[mi][u], bi);
            z = (z >= 0.f) ? z : 0.2f * z;
            mx = fmaxf(mx, z);
            sm += z;
        }
        s_red[0][tm][tn * 8 + u] = mx;
        s_red[1][tm][tn * 8 + u] = sm;
    }
    __syncthreads();
    if (tid < 128) {
        int o = tid;
        float m = -INFINITY, s = 0.f;
#pragma unroll
        for (int t = 0; t < 16; ++t) {
            m = fmaxf(m, s_red[0][t][o]);
            s += s_red[1][t][o];
        }
        int b = i0 >> 11, nt = (i0 >> 7) & 15;
        size_t base = (size_t)((b * 16 + nt) * 2) * 1024 + j0 + o;
        part[base] = m;
        part[base + 1024] = s;
    }
}

__global__ __launch_bounds__(256) void freduce_kernel(const float* __restrict__ part,
                                                      float* __restrict__ out) {
    int t = blockIdx.x * 256 + threadIdx.x;
    if (t >= 8 * 1024) return;
    int b = t >> 10, o = t & 1023;
    float m = -INFINITY, s = 0.f;
#pragma unroll
    for (int nt = 0; nt < 16; ++nt) {
        size_t base = (size_t)((b * 16 + nt) * 2) * 1024 + o;
        m = fmaxf(m, part[base]);
        s += part[base + 1024];
    }
    out[b * 2048 + o] = m;
    out[b * 2048 + 1024 + o] = s * (1.0f / 2048.0f);
}

// ---------------------------------------------------------------------------
extern "C" void kernel_launch(void* const* d_in, const int* in_sizes, int n_in,
                              void* d_out, int out_size, void* d_ws, size_t ws_size,
                              hipStream_t stream) {
    const float* points = (const float*)d_in[0];
    const float* W1 = (const float*)d_in[1];
    const float* W2 = (const float*)d_in[2];
    const float* W3 = (const float*)d_in[3];
    const float* W4 = (const float*)d_in[4];
    const float* W5 = (const float*)d_in[5];
    const float* g1 = (const float*)d_in[6];
    const float* b1 = (const float*)d_in[7];
    const float* g2 = (const float*)d_in[8];
    const float* b2 = (const float*)d_in[9];
    const float* g3 = (const float*)d_in[10];
    const float* b3 = (const float*)d_in[11];
    const float* g4 = (const float*)d_in[12];
    const float* b4 = (const float*)d_in[13];
    const float* g5 = (const float*)d_in[14];
    const float* b5 = (const float*)d_in[15];
    float* out = (float*)d_out;

    const size_t f_xcat = (size_t)BN_TOTAL * 512;
    const size_t f_x2 = BN_TOTAL;
    const size_t f_idx = (size_t)BN_TOTAL * KNN;
    const size_t f_part = (size_t)8 * 16 * 2 * 1024;
    const size_t fixedf = f_xcat + f_x2 + f_idx + f_part;
    auto needB = [&](int c) {
        size_t spq = (size_t)c * NPTS * NPTS;
        if (spq < f_xcat) spq = f_xcat;
        return 4ull * (fixedf + spq);
    };
    int cB = 2;
    if (ws_size >= needB(8)) cB = 8;
    else if (ws_size >= needB(4)) cB = 4;
    size_t spq_f = (size_t)cB * NPTS * NPTS;
    if (spq_f < f_xcat) spq_f = f_xcat;

    float* xcat = (float*)d_ws;
    float* SPQ = xcat + f_xcat;
    float* x2 = SPQ + spq_f;
    int* idx = (int*)(x2 + f_x2);
    float* part = (float*)(idx + f_idx);

    auto layer = [&](const float* xin, int C, int ldx, const float* W, int O, int oshift,
                     const float* ga, const float* be, float* xout) {
        x2_kernel<<<(BN_TOTAL + 255) / 256, 256, 0, stream>>>(xin, C, ldx, x2);
        for (int b0 = 0; b0 < BATCH; b0 += cB) {
            dist_kernel<<<dim3(16, 16, cB), 256, 0, stream>>>(xin, x2, C, ldx, b0, SPQ);
            topk_kernel<<<cB * 512, 256, 0, stream>>>(SPQ, b0, idx);
        }
        pq_gemm<<<dim3(BN_TOTAL / 64, (2 * O) / 64), 256, 0, stream>>>(xin, C, ldx, W, O, SPQ);
        int rpb = 256 >> oshift;
        gmax_kernel<<<BN_TOTAL / rpb, 256, 0, stream>>>(SPQ, idx, O, oshift, ga, be, xout, 512);
    };

    layer(points,     3,   3,   W1, 64,  6, g1, b1, xcat + 0);
    layer(xcat + 0,   64,  512, W2, 64,  6, g2, b2, xcat + 64);
    layer(xcat + 64,  64,  512, W3, 128, 7, g3, b3, xcat + 128);
    layer(xcat + 128, 128, 512, W4, 256, 8, g4, b4, xcat + 256);

    final_gemm<<<dim3(BN_TOTAL / 128, 1024 / 128), 256, 0, stream>>>(xcat, W5, g5, b5, part);
    freduce_kernel<<<(8 * 1024 + 255) / 256, 256, 0, stream>>>(part, out);
}

// Round 4
// 966.053 us; speedup vs baseline: 5.4746x; 1.1475x over previous
//
#include <hip/hip_runtime.h>
#include <math.h>

#define BATCH 8
#define NPTS 2048
#define KNN 20
#define BN_TOTAL (BATCH * NPTS)
#define EPSV 1e-5f

typedef __attribute__((ext_vector_type(8))) short short8v;   // 8 bf16
typedef __attribute__((ext_vector_type(4))) float floatx4;

// ---------------------------------------------------------------------------
// x2: per-row sum of squares
// ---------------------------------------------------------------------------
__global__ __launch_bounds__(256) void x2_kernel(const float* __restrict__ x, int C, int ldx,
                                                 float* __restrict__ x2) {
    int i = blockIdx.x * 256 + threadIdx.x;
    if (i >= BN_TOTAL) return;
    const float* xr = x + (size_t)i * ldx;
    float s = 0.f;
    if ((ldx & 3) == 0 && (C & 3) == 0) {
        const float4* xr4 = (const float4*)xr;
        for (int c = 0; c < (C >> 2); ++c) {
            float4 v = xr4[c];
            s = fmaf(v.x, v.x, s); s = fmaf(v.y, v.y, s);
            s = fmaf(v.z, v.z, s); s = fmaf(v.w, v.w, s);
        }
    } else {
        for (int c = 0; c < C; ++c) s = fmaf(xr[c], xr[c], s);
    }
    x2[i] = s;
}

// ---------------------------------------------------------------------------
// dist: tiled GEMM, neg_dist S[z*2048+i][j] = 2*dot(xi,xj) - x2i - x2j.
// 128x128 tile, BK=16, 256 thr, 8x8 micro-tile. Pad 132 (132%32=4): LDS
// write conflicts 2-way (free); float4 reads stay 16B-aligned (528=33*16).
// ---------------------------------------------------------------------------
__global__ __launch_bounds__(256) void dist_kernel(const float* __restrict__ x,
                                                   const float* __restrict__ x2,
                                                   int C, int ldx, int b0,
                                                   float* __restrict__ S) {
    __shared__ float As[16][132];
    __shared__ float Bs[16][132];
    int z = blockIdx.z;
    int b = b0 + z;
    int i0 = blockIdx.x * 128, j0 = blockIdx.y * 128;
    const float* xb = x + (size_t)b * NPTS * ldx;
    int tid = threadIdx.x;
    int tm = tid >> 4, tn = tid & 15;

    float acc[8][8] = {};
    int KT = (C + 15) >> 4;
    for (int kt = 0; kt < KT; ++kt) {
        int k0 = kt << 4;
#pragma unroll
        for (int s = tid; s < 512; s += 256) {
            int r = s >> 2, c4 = s & 3;
            int kk = k0 + c4 * 4;
            float va[4], vb[4];
            if (kk + 3 < C && (ldx & 3) == 0) {
                float4 a = *(const float4*)&xb[(size_t)(i0 + r) * ldx + kk];
                float4 bv = *(const float4*)&xb[(size_t)(j0 + r) * ldx + kk];
                va[0] = a.x; va[1] = a.y; va[2] = a.z; va[3] = a.w;
                vb[0] = bv.x; vb[1] = bv.y; vb[2] = bv.z; vb[3] = bv.w;
            } else {
#pragma unroll
                for (int u = 0; u < 4; ++u) {
                    int k = kk + u;
                    va[u] = (k < C) ? xb[(size_t)(i0 + r) * ldx + k] : 0.f;
                    vb[u] = (k < C) ? xb[(size_t)(j0 + r) * ldx + k] : 0.f;
                }
            }
#pragma unroll
            for (int u = 0; u < 4; ++u) {
                As[c4 * 4 + u][r] = va[u];
                Bs[c4 * 4 + u][r] = vb[u];
            }
        }
        __syncthreads();
#pragma unroll
        for (int k = 0; k < 16; ++k) {
            float4 a0 = *(const float4*)&As[k][tm * 8];
            float4 a1 = *(const float4*)&As[k][tm * 8 + 4];
            float4 c0 = *(const float4*)&Bs[k][tn * 8];
            float4 c1 = *(const float4*)&Bs[k][tn * 8 + 4];
            float av[8] = {a0.x, a0.y, a0.z, a0.w, a1.x, a1.y, a1.z, a1.w};
            float bv[8] = {c0.x, c0.y, c0.z, c0.w, c1.x, c1.y, c1.z, c1.w};
#pragma unroll
            for (int mi = 0; mi < 8; ++mi)
#pragma unroll
                for (int ni = 0; ni < 8; ++ni)
                    acc[mi][ni] = fmaf(av[mi], bv[ni], acc[mi][ni]);
        }
        __syncthreads();
    }

    const float* x2b = x2 + (size_t)b * NPTS;
    float xj[8];
#pragma unroll
    for (int u = 0; u < 8; ++u) xj[u] = x2b[j0 + tn * 8 + u];
#pragma unroll
    for (int mi = 0; mi < 8; ++mi) {
        float xi = x2b[i0 + tm * 8 + mi];
        float4 o0, o1;
        o0.x = 2.f * acc[mi][0] - xi - xj[0];
        o0.y = 2.f * acc[mi][1] - xi - xj[1];
        o0.z = 2.f * acc[mi][2] - xi - xj[2];
        o0.w = 2.f * acc[mi][3] - xi - xj[3];
        o1.x = 2.f * acc[mi][4] - xi - xj[4];
        o1.y = 2.f * acc[mi][5] - xi - xj[5];
        o1.z = 2.f * acc[mi][6] - xi - xj[6];
        o1.w = 2.f * acc[mi][7] - xi - xj[7];
        size_t rowp = ((size_t)z * NPTS + i0 + tm * 8 + mi) * NPTS + j0 + tn * 8;
        *(float4*)&S[rowp] = o0;
        *(float4*)&S[rowp + 4] = o1;
    }
}

// ---------------------------------------------------------------------------
// topk: one wave per row; 32 values/lane in registers; 20 shfl-argmax iters.
// ---------------------------------------------------------------------------
__global__ __launch_bounds__(256) void topk_kernel(const float* __restrict__ S, int b0,
                                                   int* __restrict__ idx_out) {
    int lane = threadIdx.x & 63, w = threadIdx.x >> 6;
    int row = blockIdx.x * 4 + w;
    const float4* S4 = (const float4*)(S + (size_t)row * NPTS);

    float v[32];
    float lm = -INFINITY; int li = 0;
#pragma unroll
    for (int r4 = 0; r4 < 8; ++r4) {
        float4 f = S4[lane * 8 + r4];
        v[r4 * 4 + 0] = f.x; v[r4 * 4 + 1] = f.y;
        v[r4 * 4 + 2] = f.z; v[r4 * 4 + 3] = f.w;
    }
#pragma unroll
    for (int q = 0; q < 32; ++q)
        if (v[q] > lm) { lm = v[q]; li = q; }

    int sel = 0;
    for (int it = 0; it < KNN; ++it) {
        float bv = lm;
        int bi = (lane << 5) | li;
#pragma unroll
        for (int d = 1; d < 64; d <<= 1) {
            float ov = __shfl_xor(bv, d);
            int oi = __shfl_xor(bi, d);
            if (ov > bv || (ov == bv && oi < bi)) { bv = ov; bi = oi; }
        }
        if (lane == it) sel = bi;
        if ((bi >> 5) == lane) {
            int r = bi & 31;
#pragma unroll
            for (int q = 0; q < 32; ++q)
                if (q == r) v[q] = -INFINITY;
            lm = -INFINITY; li = 0;
#pragma unroll
            for (int q = 0; q < 32; ++q)
                if (v[q] > lm) { lm = v[q]; li = q; }
        }
    }
    int z = row >> 11, i = row & 2047;
    int bn = (b0 + z) * NPTS + i;
    if (lane < KNN) idx_out[bn * KNN + lane] = sel;
}

// ---------------------------------------------------------------------------
// pq_gemm: PQ[bn][0..O)=x.Wp^T, PQ[bn][O..2O)=x.Wq^T as one GEMM (N=2O).
// ---------------------------------------------------------------------------
__global__ __launch_bounds__(256) void pq_gemm(const float* __restrict__ X, int C, int ldx,
                                               const float* __restrict__ W, int O,
                                               float* __restrict__ PQ) {
    __shared__ float As[32][68];
    __shared__ float Bs[32][68];
    int i0 = blockIdx.x * 64, j0 = blockIdx.y * 64;
    int tid = threadIdx.x;
    int tm = tid >> 4, tn = tid & 15;
    int N2 = 2 * O;

    float acc[4][4] = {};
    int KT = (C + 31) >> 5;
    for (int kt = 0; kt < KT; ++kt) {
        int k0 = kt << 5;
        for (int e = tid; e < 2048; e += 256) {
            int m = e >> 5, k = e & 31;
            int kk = k0 + k;
            As[k][m] = (kk < C) ? X[(size_t)(i0 + m) * ldx + kk] : 0.f;
            int o = j0 + m;
            float wv = 0.f;
            if (kk < C)
                wv = (o < O) ? W[(size_t)o * 2 * C + kk] : W[(size_t)(o - O) * 2 * C + C + kk];
            Bs[k][m] = wv;
        }
        __syncthreads();
#pragma unroll
        for (int k = 0; k < 32; ++k) {
            float4 a = *(const float4*)&As[k][tm * 4];
            float4 bb = *(const float4*)&Bs[k][tn * 4];
            float av[4] = {a.x, a.y, a.z, a.w};
            float bv[4] = {bb.x, bb.y, bb.z, bb.w};
#pragma unroll
            for (int mi = 0; mi < 4; ++mi)
#pragma unroll
                for (int ni = 0; ni < 4; ++ni)
                    acc[mi][ni] = fmaf(av[mi], bv[ni], acc[mi][ni]);
        }
        __syncthreads();
    }
#pragma unroll
    for (int mi = 0; mi < 4; ++mi) {
        float4 o;
        o.x = acc[mi][0]; o.y = acc[mi][1]; o.z = acc[mi][2]; o.w = acc[mi][3];
        *(float4*)&PQ[(size_t)(i0 + tm * 4 + mi) * N2 + j0 + tn * 4] = o;
    }
}

// ---------------------------------------------------------------------------
// gather-max + BN + LeakyReLU epilogue. 256/O rows per block, all lanes busy.
// ---------------------------------------------------------------------------
__global__ __launch_bounds__(256) void gmax_kernel(const float* __restrict__ PQ,
                                                   const int* __restrict__ idx, int O, int oshift,
                                                   const float* __restrict__ gamma,
                                                   const float* __restrict__ beta,
                                                   float* __restrict__ out, int ldo) {
    __shared__ int s_idx[4][KNN];
    int rpb = 256 >> oshift;                 // O in {64,128,256}
    int lr = threadIdx.x >> oshift;
    int o = threadIdx.x & (O - 1);
    int bn = blockIdx.x * rpb + lr;
    int b = bn >> 11;
    if (o < KNN) s_idx[lr][o] = idx[bn * KNN + o];
    __syncthreads();
    const float inv = 1.0f / sqrtf(1.0f + EPSV);
    int N2 = 2 * O;
    size_t brow = (size_t)(b << 11);
    float mx = -INFINITY, mn = INFINITY;
#pragma unroll
    for (int k = 0; k < KNN; ++k) {
        float v = PQ[(brow + s_idx[lr][k]) * N2 + o];
        mx = fmaxf(mx, v);
        mn = fminf(mn, v);
    }
    float pn = PQ[(size_t)bn * N2 + o];
    float qn = PQ[(size_t)bn * N2 + O + o];
    float sc = gamma[o] * inv;
    float m = (sc >= 0.f) ? mx : mn;
    float z = sc * (m - pn + qn) + beta[o];
    out[(size_t)bn * ldo + o] = (z >= 0.f) ? z : 0.2f * z;
}

// ---------------------------------------------------------------------------
// split_bf16: x -> (hi, lo) bf16 pair, RNE. hi+lo reproduces x to ~2^-16 rel.
// ---------------------------------------------------------------------------
__device__ __forceinline__ unsigned short bf16_rne(float x) {
    union { float f; unsigned u; } cv; cv.f = x;
    unsigned r = (cv.u + 0x7fffu + ((cv.u >> 16) & 1u)) >> 16;
    return (unsigned short)r;
}
__global__ __launch_bounds__(256) void split_bf16_kernel(const float* __restrict__ in, int n4,
                                                         unsigned short* __restrict__ hi,
                                                         unsigned short* __restrict__ lo) {
    int i = blockIdx.x * 256 + threadIdx.x;
    if (i >= n4) return;
    float4 v = ((const float4*)in)[i];
    float vv[4] = {v.x, v.y, v.z, v.w};
    ushort4 h, l;
    unsigned short hh[4], ll[4];
#pragma unroll
    for (int u = 0; u < 4; ++u) {
        unsigned short hb = bf16_rne(vv[u]);
        union { unsigned u32; float f; } hf; hf.u32 = ((unsigned)hb) << 16;
        hh[u] = hb;
        ll[u] = bf16_rne(vv[u] - hf.f);
    }
    h.x = hh[0]; h.y = hh[1]; h.z = hh[2]; h.w = hh[3];
    l.x = ll[0]; l.y = ll[1]; l.z = ll[2]; l.w = ll[3];
    *(ushort4*)(hi + (size_t)i * 4) = h;
    *(ushort4*)(lo + (size_t)i * 4) = l;
}

// ---------------------------------------------------------------------------
// final MFMA GEMM: feat = lrelu(bn(X @ W5^T)) with split-bf16 (3 K-segments:
// Xhi.Whi + Xhi.Wlo + Xlo.Whi), fused partial max/sum over the 128 n-rows.
// 128x128 tile, BK=32, 4 waves (2x2), each wave 4x4 frags of 16x16x32.
// LDS XOR-swizzle (byte ^= (row&7)<<4) on both write and read sides.
// ---------------------------------------------------------------------------
__global__ __launch_bounds__(256) void final_mfma(const unsigned short* __restrict__ Xhi,
                                                  const unsigned short* __restrict__ Xlo,
                                                  const unsigned short* __restrict__ Whi,
                                                  const unsigned short* __restrict__ Wlo,
                                                  const float* __restrict__ g5,
                                                  const float* __restrict__ b5,
                                                  float* __restrict__ part) {
    __shared__ __align__(16) char As[128 * 64];   // [row][32 bf16] swizzled
    __shared__ __align__(16) char Bs[128 * 64];
    __shared__ float sredM[2][128];
    __shared__ float sredS[2][128];

    int tid = threadIdx.x;
    int i0 = blockIdx.x * 128;
    int j0 = blockIdx.y * 128;
    int lane = tid & 63, w = tid >> 6;
    int wr = w >> 1, wc = w & 1;

    // staging assignment: thread -> (row, 16B-quarter), two rows apart 64
    int rowA = tid >> 2, q = tid & 3;
    auto swz = [](int row, int qq) { return (row * 64 + qq * 16) ^ ((row & 7) << 4); };
    int wa0 = swz(rowA, q), wa1 = swz(rowA + 64, q);

    // fragment LDS byte offsets (swizzled)
    int fr = lane & 15, slot = lane >> 4;
    int aoff[4], boff[4];
#pragma unroll
    for (int m = 0; m < 4; ++m) {
        int ra = wr * 64 + m * 16 + fr;
        aoff[m] = (ra * 64 + slot * 16) ^ ((ra & 7) << 4);
        int rb = wc * 64 + m * 16 + fr;
        boff[m] = (rb * 64 + slot * 16) ^ ((rb & 7) << 4);
    }

    floatx4 acc[4][4];
#pragma unroll
    for (int m = 0; m < 4; ++m)
#pragma unroll
        for (int n = 0; n < 4; ++n)
            acc[m][n] = (floatx4){0.f, 0.f, 0.f, 0.f};

    uint4 ra0, ra1, rb0, rb1;
    auto prefetch = [&](int it) {
        int seg = it >> 4;
        int kk = (it & 15) * 32;
        const unsigned short* Ab = ((seg < 2) ? Xhi : Xlo) + (size_t)i0 * 512 + kk + q * 8;
        const unsigned short* Bb = ((seg == 1) ? Wlo : Whi) + (size_t)j0 * 512 + kk + q * 8;
        ra0 = *(const uint4*)(Ab + (size_t)rowA * 512);
        ra1 = *(const uint4*)(Ab + (size_t)(rowA + 64) * 512);
        rb0 = *(const uint4*)(Bb + (size_t)rowA * 512);
        rb1 = *(const uint4*)(Bb + (size_t)(rowA + 64) * 512);
    };

    prefetch(0);
    for (int it = 0; it < 48; ++it) {
        __syncthreads();
        *(uint4*)(As + wa0) = ra0;
        *(uint4*)(As + wa1) = ra1;
        *(uint4*)(Bs + wa0) = rb0;
        *(uint4*)(Bs + wa1) = rb1;
        __syncthreads();
        if (it < 47) prefetch(it + 1);
        short8v af[4], bf[4];
#pragma unroll
        for (int m = 0; m < 4; ++m) af[m] = *(const short8v*)(As + aoff[m]);
#pragma unroll
        for (int n = 0; n < 4; ++n) bf[n] = *(const short8v*)(Bs + boff[n]);
#pragma unroll
        for (int m = 0; m < 4; ++m)
#pragma unroll
            for (int n = 0; n < 4; ++n)
                acc[m][n] = __builtin_amdgcn_mfma_f32_16x16x32_bf16(af[m], bf[n], acc[m][n], 0, 0, 0);
    }

    // epilogue: BN + lrelu + per-column (max,sum) over this block's 128 rows
    const float inv = 1.0f / sqrtf(1.0f + EPSV);
#pragma unroll
    for (int n = 0; n < 4; ++n) {
        int o = j0 + wc * 64 + n * 16 + fr;
        float sc = g5[o] * inv;
        float bi = b5[o];
        float mx = -INFINITY, sm = 0.f;
#pragma unroll
        for (int m = 0; m < 4; ++m)
#pragma unroll
            for (int r = 0; r < 4; ++r) {
                float z = fmaf(sc, acc[m][n][r], bi);
                z = (z >= 0.f) ? z : 0.2f * z;
                mx = fmaxf(mx, z);
                sm += z;
            }
#pragma unroll
        for (int d = 16; d < 64; d <<= 1) {
            mx = fmaxf(mx, __shfl_xor(mx, d));
            sm += __shfl_xor(sm, d);
        }
        if (slot == 0) {
            sredM[wr][wc * 64 + n * 16 + fr] = mx;
            sredS[wr][wc * 64 + n * 16 + fr] = sm;
        }
    }
    __syncthreads();
    if (tid < 128) {
        float m = fmaxf(sredM[0][tid], sredM[1][tid]);
        float s = sredS[0][tid] + sredS[1][tid];
        int b = i0 >> 11, nt = (i0 >> 7) & 15;
        size_t base = (size_t)((b * 16 + nt) * 2) * 1024 + j0 + tid;
        part[base] = m;
        part[base + 1024] = s;
    }
}

__global__ __launch_bounds__(256) void freduce_kernel(const float* __restrict__ part,
                                                      float* __restrict__ out) {
    int t = blockIdx.x * 256 + threadIdx.x;
    if (t >= 8 * 1024) return;
    int b = t >> 10, o = t & 1023;
    float m = -INFINITY, s = 0.f;
#pragma unroll
    for (int nt = 0; nt < 16; ++nt) {
        size_t base = (size_t)((b * 16 + nt) * 2) * 1024 + o;
        m = fmaxf(m, part[base]);
        s += part[base + 1024];
    }
    out[b * 2048 + o] = m;
    out[b * 2048 + 1024 + o] = s * (1.0f / 2048.0f);
}

// ---------------------------------------------------------------------------
extern "C" void kernel_launch(void* const* d_in, const int* in_sizes, int n_in,
                              void* d_out, int out_size, void* d_ws, size_t ws_size,
                              hipStream_t stream) {
    const float* points = (const float*)d_in[0];
    const float* W1 = (const float*)d_in[1];
    const float* W2 = (const float*)d_in[2];
    const float* W3 = (const float*)d_in[3];
    const float* W4 = (const float*)d_in[4];
    const float* W5 = (const float*)d_in[5];
    const float* g1 = (const float*)d_in[6];
    const float* b1 = (const float*)d_in[7];
    const float* g2 = (const float*)d_in[8];
    const float* b2 = (const float*)d_in[9];
    const float* g3 = (const float*)d_in[10];
    const float* b3 = (const float*)d_in[11];
    const float* g4 = (const float*)d_in[12];
    const float* b4 = (const float*)d_in[13];
    const float* g5 = (const float*)d_in[14];
    const float* b5 = (const float*)d_in[15];
    float* out = (float*)d_out;

    const size_t f_xcat = (size_t)BN_TOTAL * 512;          // 8,388,608 floats
    const size_t f_w5 = (size_t)1024 * 512;                // 524,288 elems
    const size_t f_x2 = BN_TOTAL;
    const size_t f_idx = (size_t)BN_TOTAL * KNN;
    const size_t f_part = (size_t)8 * 16 * 2 * 1024;
    // bf16 split buffers: Xhi+Xlo = f_xcat ushorts each -> f_xcat floats total;
    // Whi+Wlo -> f_w5/2*2 = f_w5 floats total... (2 ushort = 1 float)
    const size_t f_bf16 = f_xcat + f_w5;                   // in float units
    const size_t fixedf = f_xcat + f_x2 + f_idx + f_part + f_bf16;
    auto needB = [&](int c) {
        size_t spq = (size_t)c * NPTS * NPTS;
        if (spq < f_xcat) spq = f_xcat;
        return 4ull * (fixedf + spq);
    };
    int cB = 2;
    if (ws_size >= needB(8)) cB = 8;
    else if (ws_size >= needB(4)) cB = 4;
    size_t spq_f = (size_t)cB * NPTS * NPTS;
    if (spq_f < f_xcat) spq_f = f_xcat;

    float* xcat = (float*)d_ws;
    float* SPQ = xcat + f_xcat;
    float* x2 = SPQ + spq_f;
    int* idx = (int*)(x2 + f_x2);
    float* part = (float*)(idx + f_idx);
    unsigned short* Xhi = (unsigned short*)(part + f_part);
    unsigned short* Xlo = Xhi + f_xcat;
    unsigned short* Whi = Xlo + f_xcat;
    unsigned short* Wlo = Whi + f_w5;

    auto layer = [&](const float* xin, int C, int ldx, const float* W, int O, int oshift,
                     const float* ga, const float* be, float* xout) {
        x2_kernel<<<(BN_TOTAL + 255) / 256, 256, 0, stream>>>(xin, C, ldx, x2);
        for (int b0 = 0; b0 < BATCH; b0 += cB) {
            dist_kernel<<<dim3(16, 16, cB), 256, 0, stream>>>(xin, x2, C, ldx, b0, SPQ);
            topk_kernel<<<cB * 512, 256, 0, stream>>>(SPQ, b0, idx);
        }
        pq_gemm<<<dim3(BN_TOTAL / 64, (2 * O) / 64), 256, 0, stream>>>(xin, C, ldx, W, O, SPQ);
        int rpb = 256 >> oshift;
        gmax_kernel<<<BN_TOTAL / rpb, 256, 0, stream>>>(SPQ, idx, O, oshift, ga, be, xout, 512);
    };

    layer(points,     3,   3,   W1, 64,  6, g1, b1, xcat + 0);
    layer(xcat + 0,   64,  512, W2, 64,  6, g2, b2, xcat + 64);
    layer(xcat + 64,  64,  512, W3, 128, 7, g3, b3, xcat + 128);
    layer(xcat + 128, 128, 512, W4, 256, 8, g4, b4, xcat + 256);

    split_bf16_kernel<<<(int)((f_xcat / 4 + 255) / 256), 256, 0, stream>>>(xcat, (int)(f_xcat / 4), Xhi, Xlo);
    split_bf16_kernel<<<(int)((f_w5 / 4 + 255) / 256), 256, 0, stream>>>(W5, (int)(f_w5 / 4), Whi, Wlo);
    final_mfma<<<dim3(BN_TOTAL / 128, 1024 / 128), 256, 0, stream>>>(Xhi, Xlo, Whi, Wlo, g5, b5, part);
    freduce_kernel<<<(8 * 1024 + 255) / 256, 256, 0, stream>>>(part, out);
}